// Round 8
// baseline (348.706 us; speedup 1.0000x reference)
//
#include <hip/hip_runtime.h>
#include <hip/hip_bf16.h>
#include <float.h>

// MixMIL fused kernel set.
// Shapes (fixed by setup_inputs): I=512000, Q=128, P=1, S=8 (C=8 channels), N=4000.
// d_in: x[I,Q] f32, beta_u[Q,1,8] f32, beta_z[Q,1,8] f32, i[I] int32 (sorted), n_bags
// d_out: [N,1,8] f32.
//
// Algebra: eta = beta_z/b and out = b*(xmil-mean)/std. std scales linearly with
// the positive per-channel b, so accumulating with raw beta_z (v = x.beta_z)
// gives xmil' = b*xmil and b*(xmil'-mean')/std' == b*(xmil-mean)/std. b only
// multiplies at the very end.
//
// R8: R7's proj4 SPILLED (VGPR_Count=84 < ~128 live regs -> scratch traffic,
// 165us). Revert to 2-rows/thread chunk-16 proj (110 live regs) and pin the
// budget with __launch_bounds__(256,4) (cap 128 VGPR, 4 waves/SIMD). Keep the
// R6 fusions: bounds in proj prologue, stats+out fused. 3 kernels total.

#define QDIM 128
#define C8 8

__device__ __forceinline__ void dot4(float& acc, const float4 a, const float4 b) {
    acc = fmaf(a.x, b.x, acc);
    acc = fmaf(a.y, b.y, acc);
    acc = fmaf(a.z, b.z, acc);
    acc = fmaf(a.w, b.w, acc);
}

// Pass 1: uz[r][0..7] = x[r].beta_u[:,c], uz[r][8..15] = x[r].beta_z[:,c].
// Thread g handles rows g and g+halfI (chunk=16 floats = 1 full cache line per
// row per iter). Bag boundaries filled in the prologue (grid-stride).
__global__ __launch_bounds__(256, 4) void mixmil_proj(
    const float* __restrict__ x,
    const float* __restrict__ bu,
    const float* __restrict__ bz,
    const int*   __restrict__ seg,
    int I, int N,
    int* __restrict__ bs,
    float* __restrict__ uz)
{
    const int t    = threadIdx.x;
    const int gtid = blockIdx.x * 256 + t;
    const int nthr = gridDim.x * 256;

    // Fused bounds: bs[j] = first k with seg[k] >= j; bs[N] = I.
    for (int k = gtid; k <= I; k += nthr) {
        int a    = (k < I) ? seg[k]     : N;
        int prev = (k > 0) ? seg[k - 1] : -1;
        for (int j = prev + 1; j <= a; ++j) bs[j] = k;
    }

    __shared__ float WT[16][QDIM];  // rows 0..7: beta_u^T, rows 8..15: beta_z^T
    for (int j = t; j < QDIM * 16; j += 256) {
        int s = j >> 7, q = j & 127;
        WT[s][q] = (s < 8) ? bu[q * 8 + s] : bz[q * 8 + (s - 8)];
    }
    __syncthreads();

    const int halfI = I >> 1;
    const int g = gtid;
    if (g >= halfI) return;

    const float* xr1 = x + (size_t)g * QDIM;
    const float* xr2 = xr1 + (size_t)halfI * QDIM;

    float du1[8], dv1[8], du2[8], dv2[8];
#pragma unroll
    for (int c = 0; c < 8; ++c) { du1[c] = dv1[c] = du2[c] = dv2[c] = 0.f; }

    float4 A0[4], B0[4], A1[4], B1[4];
#pragma unroll
    for (int j = 0; j < 4; ++j) {
        A0[j] = *(const float4*)(xr1 + 4 * j);
        B0[j] = *(const float4*)(xr2 + 4 * j);
    }

#pragma unroll
    for (int q0 = 0; q0 < QDIM; q0 += 16) {
        // prefetch next chunk while computing current
        if (q0 + 16 < QDIM) {
#pragma unroll
            for (int j = 0; j < 4; ++j) {
                A1[j] = *(const float4*)(xr1 + q0 + 16 + 4 * j);
                B1[j] = *(const float4*)(xr2 + q0 + 16 + 4 * j);
            }
        }
#pragma unroll
        for (int c = 0; c < 8; ++c) {
#pragma unroll
            for (int j = 0; j < 4; ++j) {
                const float4 wu = *(const float4*)&WT[c][q0 + 4 * j];      // broadcast
                const float4 wz = *(const float4*)&WT[8 + c][q0 + 4 * j];  // broadcast
                dot4(du1[c], A0[j], wu);
                dot4(dv1[c], A0[j], wz);
                dot4(du2[c], B0[j], wu);
                dot4(dv2[c], B0[j], wz);
            }
        }
#pragma unroll
        for (int j = 0; j < 4; ++j) { A0[j] = A1[j]; B0[j] = B1[j]; }
    }

    float4* o1 = (float4*)(uz + (size_t)g * 16);
    float4* o2 = (float4*)(uz + ((size_t)g + halfI) * 16);
    o1[0] = make_float4(du1[0], du1[1], du1[2], du1[3]);
    o1[1] = make_float4(du1[4], du1[5], du1[6], du1[7]);
    o1[2] = make_float4(dv1[0], dv1[1], dv1[2], dv1[3]);
    o1[3] = make_float4(dv1[4], dv1[5], dv1[6], dv1[7]);
    o2[0] = make_float4(du2[0], du2[1], du2[2], du2[3]);
    o2[1] = make_float4(du2[4], du2[5], du2[6], du2[7]);
    o2[2] = make_float4(dv2[0], dv2[1], dv2[2], dv2[3]);
    o2[3] = make_float4(dv2[4], dv2[5], dv2[6], dv2[7]);
}

// Pass 2: one bag per wave, online softmax + weighted sum over uz rows.
__global__ __launch_bounds__(256) void mixmil_bags2(
    const float* __restrict__ uz,
    const int*   __restrict__ bs,
    int N,
    float* __restrict__ xmil)  // [N,8]
{
    const int wave = threadIdx.x >> 6;
    const int lane = threadIdx.x & 63;
    const int n = blockIdx.x * 4 + wave;
    if (n >= N) return;

    const int lo = bs[n];
    const int hi = bs[n + 1];

    float mM[8], lL[8], aA[8];
#pragma unroll
    for (int c = 0; c < 8; ++c) { mM[c] = -1e30f; lL[c] = 0.f; aA[c] = 0.f; }

    for (int k = lo + lane; k < hi; k += 64) {
        const float4* r = (const float4*)(uz + (size_t)k * 16);
        float4 u0 = r[0], u1 = r[1], v0 = r[2], v1 = r[3];
        float uu[8] = {u0.x, u0.y, u0.z, u0.w, u1.x, u1.y, u1.z, u1.w};
        float vv[8] = {v0.x, v0.y, v0.z, v0.w, v1.x, v1.y, v1.z, v1.w};
#pragma unroll
        for (int c = 0; c < 8; ++c) {
            float u = uu[c], v = vv[c];
            float nm = fmaxf(mM[c], u);
            float sc = __expf(mM[c] - nm);
            float p  = __expf(u - nm);
            lL[c] = lL[c] * sc + p;
            aA[c] = aA[c] * sc + p * v;
            mM[c] = nm;
        }
    }

    // Butterfly merge across the 64 lanes of this wave.
    for (int off = 32; off; off >>= 1) {
#pragma unroll
        for (int c = 0; c < 8; ++c) {
            float m2 = __shfl_xor(mM[c], off);
            float l2 = __shfl_xor(lL[c], off);
            float a2 = __shfl_xor(aA[c], off);
            float nm = fmaxf(mM[c], m2);
            float s1 = __expf(mM[c] - nm);
            float s2 = __expf(m2 - nm);
            lL[c] = lL[c] * s1 + l2 * s2;
            aA[c] = aA[c] * s1 + a2 * s2;
            mM[c] = nm;
        }
    }

    if (lane == 0) {
        const bool nonempty = hi > lo;
#pragma unroll
        for (int c = 0; c < 8; ++c)
            xmil[(size_t)n * 8 + c] = nonempty ? (aA[c] / lL[c]) : 0.f;
    }
}

// Pass 3: fused stats + output. Every block redundantly computes the
// per-channel mean / rstd (ddof=1) over xmil (128 KB, L2/L3-hot) and
// b = rms(beta_z), then writes its 256-element slice of out.
__global__ __launch_bounds__(256) void mixmil_statsout(
    const float* __restrict__ xmil,
    const float* __restrict__ bz,
    int N, int total,
    float* __restrict__ out)
{
    double s[8], qq[8];
    float t2[8];
#pragma unroll
    for (int c = 0; c < 8; ++c) { s[c] = 0.0; qq[c] = 0.0; t2[c] = 0.f; }

    for (int r = threadIdx.x; r < N; r += 256) {
        const float* row = xmil + (size_t)r * 8;
#pragma unroll
        for (int c = 0; c < 8; ++c) {
            float v = row[c];
            s[c] += v;
            qq[c] += (double)v * (double)v;
        }
    }
    for (int r = threadIdx.x; r < QDIM; r += 256) {
        const float* row = bz + (size_t)r * 8;
#pragma unroll
        for (int c = 0; c < 8; ++c) { float v = row[c]; t2[c] = fmaf(v, v, t2[c]); }
    }

    // wave reduce (width 64)
    for (int off = 32; off; off >>= 1) {
#pragma unroll
        for (int c = 0; c < 8; ++c) {
            s[c]  += __shfl_xor(s[c], off);
            qq[c] += __shfl_xor(qq[c], off);
            t2[c] += __shfl_xor(t2[c], off);
        }
    }

    __shared__ double S[4][8], QQ[4][8];
    __shared__ float T2[4][8];
    __shared__ float fb[8], fm[8], fr[8];
    const int w = threadIdx.x >> 6;
    if ((threadIdx.x & 63) == 0) {
#pragma unroll
        for (int c = 0; c < 8; ++c) { S[w][c] = s[c]; QQ[w][c] = qq[c]; T2[w][c] = t2[c]; }
    }
    __syncthreads();
    if (threadIdx.x < 8) {
        const int c = threadIdx.x;
        double ss = S[0][c] + S[1][c] + S[2][c] + S[3][c];
        double qs = QQ[0][c] + QQ[1][c] + QQ[2][c] + QQ[3][c];
        float  tt = T2[0][c] + T2[1][c] + T2[2][c] + T2[3][c];
        double mean = ss / (double)N;
        double var  = (qs - ss * ss / (double)N) / (double)(N - 1);
        fb[c] = sqrtf(tt / (float)QDIM);        // b
        fm[c] = (float)mean;
        fr[c] = (float)(1.0 / sqrt(var));       // rstd
    }
    __syncthreads();

    const int e = blockIdx.x * 256 + threadIdx.x;
    if (e < total) {
        const int c = e & 7;
        out[e] = fb[c] * (xmil[e] - fm[c]) * fr[c];
    }
}

extern "C" void kernel_launch(void* const* d_in, const int* in_sizes, int n_in,
                              void* d_out, int out_size, void* d_ws, size_t ws_size,
                              hipStream_t stream) {
    const float* x  = (const float*)d_in[0];
    const float* bu = (const float*)d_in[1];
    const float* bz = (const float*)d_in[2];
    const int*   sg = (const int*)d_in[3];   // sorted bag ids (int32)

    const int I = in_sizes[0] / QDIM;        // 512000
    const int N = out_size / C8;             // 4000 bags
    const int halfI = I >> 1;                // 256000

    // ws layout: uz[I*16] | xmil[N*8] | bs[N+1]   (ws ~1 GB, ~33 MB used)
    float* uz   = (float*)d_ws;
    float* xmil = uz + (size_t)I * 16;
    int*   bs   = (int*)(xmil + (size_t)N * C8);

    mixmil_proj<<<(halfI + 255) / 256, 256, 0, stream>>>(x, bu, bz, sg, I, N, bs, uz);

    mixmil_bags2<<<(N + 3) / 4, 256, 0, stream>>>(uz, bs, N, xmil);

    const int total = N * C8;
    mixmil_statsout<<<(total + 255) / 256, 256, 0, stream>>>(
        xmil, bz, N, total, (float*)d_out);
}

// Round 9
// 125.913 us; speedup vs baseline: 2.7694x; 2.7694x over previous
//
#include <hip/hip_runtime.h>
#include <hip/hip_bf16.h>
#include <float.h>

// MixMIL fused kernel set.
// Shapes (fixed by setup_inputs): I=512000, Q=128, P=1, S=8 (C=8 channels), N=4000.
// d_in: x[I,Q] f32, beta_u[Q,1,8] f32, beta_z[Q,1,8] f32, i[I] int32 (sorted), n_bags
// d_out: [N,1,8] f32.
//
// Algebra: eta = beta_z/b and out = b*(xmil-mean)/std. std scales linearly with
// the positive per-channel b, so accumulating with raw beta_z (v = x.beta_z)
// gives xmil' = b*xmil and b*(xmil'-mean')/std' == b*(xmil-mean)/std. b only
// multiplies at the very end.
//
// R9 (R7: default VGPR cap 84 spilled; R8: launch_bounds(256,4) made the
// allocator chase 8 waves/EU -> 64 VGPR, worse):
//  - amdgpu_waves_per_eu(3,3): exact pin, ~170-VGPR budget, no spills, no
//    occupancy-chasing. ~140 live regs for 4 rows x 16-float chunks.
//  - Weights read via wave-UNIFORM indices straight from global bu/bz ->
//    compiler scalarizes to s_load + SGPR-operand FMAs. No LDS, no staging,
//    no __syncthreads. (Worst case: uniform-address L1 broadcast = LDS-speed.)
//  - 4 rows/thread: weight fetch amortized over 4 rows.

#define QDIM 128
#define C8 8

// compile-time float4 component extract (k is a constant after full unroll)
__device__ __forceinline__ float f4c(const float4& v, int k) {
    switch (k & 3) {
        case 0: return v.x;
        case 1: return v.y;
        case 2: return v.z;
        default: return v.w;
    }
}

// Pass 1: uz[r][0..7] = x[r].beta_u[:,c], uz[r][8..15] = x[r].beta_z[:,c].
// Thread g handles rows g, g+qI, g+2qI, g+3qI. Bag bounds filled in prologue.
__global__ __launch_bounds__(256)
__attribute__((amdgpu_waves_per_eu(3, 3)))
void mixmil_proj(
    const float* __restrict__ x,
    const float* __restrict__ bu,
    const float* __restrict__ bz,
    const int*   __restrict__ seg,
    int I, int N,
    int* __restrict__ bs,
    float* __restrict__ uz)
{
    const int t    = threadIdx.x;
    const int gtid = blockIdx.x * 256 + t;
    const int nthr = gridDim.x * 256;

    // Fused bounds: bs[j] = first k with seg[k] >= j; bs[N] = I.
    for (int k = gtid; k <= I; k += nthr) {
        int a    = (k < I) ? seg[k]     : N;
        int prev = (k > 0) ? seg[k - 1] : -1;
        for (int j = prev + 1; j <= a; ++j) bs[j] = k;
    }

    const int qI = I >> 2;
    const int g  = gtid;

    if (g < qI) {
        const float* xr[4];
#pragma unroll
        for (int r = 0; r < 4; ++r) xr[r] = x + (size_t)(g + r * qI) * QDIM;

        float du[4][8], dv[4][8];
#pragma unroll
        for (int r = 0; r < 4; ++r)
#pragma unroll
            for (int c = 0; c < 8; ++c) { du[r][c] = 0.f; dv[r][c] = 0.f; }

#pragma unroll
        for (int q0 = 0; q0 < QDIM; q0 += 16) {
            // 64B-granular per-lane x loads: 4 consecutive float4 per row.
            float4 xa[4][4];
#pragma unroll
            for (int r = 0; r < 4; ++r)
#pragma unroll
                for (int j = 0; j < 4; ++j)
                    xa[r][j] = *(const float4*)(xr[r] + q0 + 4 * j);

#pragma unroll
            for (int qq = 0; qq < 16; ++qq) {
                const int q = q0 + qq;
                // Wave-uniform weight reads (scalarize to s_load):
                const float4 U0 = *(const float4*)(bu + q * 8);
                const float4 U1 = *(const float4*)(bu + q * 8 + 4);
                const float4 Z0 = *(const float4*)(bz + q * 8);
                const float4 Z1 = *(const float4*)(bz + q * 8 + 4);
#pragma unroll
                for (int r = 0; r < 4; ++r) {
                    const float xv = f4c(xa[r][qq >> 2], qq);
                    du[r][0] = fmaf(xv, U0.x, du[r][0]);
                    du[r][1] = fmaf(xv, U0.y, du[r][1]);
                    du[r][2] = fmaf(xv, U0.z, du[r][2]);
                    du[r][3] = fmaf(xv, U0.w, du[r][3]);
                    du[r][4] = fmaf(xv, U1.x, du[r][4]);
                    du[r][5] = fmaf(xv, U1.y, du[r][5]);
                    du[r][6] = fmaf(xv, U1.z, du[r][6]);
                    du[r][7] = fmaf(xv, U1.w, du[r][7]);
                    dv[r][0] = fmaf(xv, Z0.x, dv[r][0]);
                    dv[r][1] = fmaf(xv, Z0.y, dv[r][1]);
                    dv[r][2] = fmaf(xv, Z0.z, dv[r][2]);
                    dv[r][3] = fmaf(xv, Z0.w, dv[r][3]);
                    dv[r][4] = fmaf(xv, Z1.x, dv[r][4]);
                    dv[r][5] = fmaf(xv, Z1.y, dv[r][5]);
                    dv[r][6] = fmaf(xv, Z1.z, dv[r][6]);
                    dv[r][7] = fmaf(xv, Z1.w, dv[r][7]);
                }
            }
        }

#pragma unroll
        for (int r = 0; r < 4; ++r) {
            float4* o = (float4*)(uz + (size_t)(g + r * qI) * 16);
            o[0] = make_float4(du[r][0], du[r][1], du[r][2], du[r][3]);
            o[1] = make_float4(du[r][4], du[r][5], du[r][6], du[r][7]);
            o[2] = make_float4(dv[r][0], dv[r][1], dv[r][2], dv[r][3]);
            o[3] = make_float4(dv[r][4], dv[r][5], dv[r][6], dv[r][7]);
        }
    }

    // Tail rows (I % 4, never taken for I=512000).
    const int tail = I - (qI << 2);
    if (g < tail) {
        const int row = (qI << 2) + g;
        const float* xr = x + (size_t)row * QDIM;
        float du[8], dv[8];
#pragma unroll
        for (int c = 0; c < 8; ++c) { du[c] = 0.f; dv[c] = 0.f; }
        for (int q = 0; q < QDIM; ++q) {
            float xv = xr[q];
#pragma unroll
            for (int c = 0; c < 8; ++c) {
                du[c] = fmaf(xv, bu[q * 8 + c], du[c]);
                dv[c] = fmaf(xv, bz[q * 8 + c], dv[c]);
            }
        }
        float* o = uz + (size_t)row * 16;
#pragma unroll
        for (int c = 0; c < 8; ++c) { o[c] = du[c]; o[8 + c] = dv[c]; }
    }
}

// Pass 2: one bag per wave, online softmax + weighted sum over uz rows.
__global__ __launch_bounds__(256) void mixmil_bags2(
    const float* __restrict__ uz,
    const int*   __restrict__ bs,
    int N,
    float* __restrict__ xmil)  // [N,8]
{
    const int wave = threadIdx.x >> 6;
    const int lane = threadIdx.x & 63;
    const int n = blockIdx.x * 4 + wave;
    if (n >= N) return;

    const int lo = bs[n];
    const int hi = bs[n + 1];

    float mM[8], lL[8], aA[8];
#pragma unroll
    for (int c = 0; c < 8; ++c) { mM[c] = -1e30f; lL[c] = 0.f; aA[c] = 0.f; }

    for (int k = lo + lane; k < hi; k += 64) {
        const float4* r = (const float4*)(uz + (size_t)k * 16);
        float4 u0 = r[0], u1 = r[1], v0 = r[2], v1 = r[3];
        float uu[8] = {u0.x, u0.y, u0.z, u0.w, u1.x, u1.y, u1.z, u1.w};
        float vv[8] = {v0.x, v0.y, v0.z, v0.w, v1.x, v1.y, v1.z, v1.w};
#pragma unroll
        for (int c = 0; c < 8; ++c) {
            float u = uu[c], v = vv[c];
            float nm = fmaxf(mM[c], u);
            float sc = __expf(mM[c] - nm);
            float p  = __expf(u - nm);
            lL[c] = lL[c] * sc + p;
            aA[c] = aA[c] * sc + p * v;
            mM[c] = nm;
        }
    }

    // Butterfly merge across the 64 lanes of this wave.
    for (int off = 32; off; off >>= 1) {
#pragma unroll
        for (int c = 0; c < 8; ++c) {
            float m2 = __shfl_xor(mM[c], off);
            float l2 = __shfl_xor(lL[c], off);
            float a2 = __shfl_xor(aA[c], off);
            float nm = fmaxf(mM[c], m2);
            float s1 = __expf(mM[c] - nm);
            float s2 = __expf(m2 - nm);
            lL[c] = lL[c] * s1 + l2 * s2;
            aA[c] = aA[c] * s1 + a2 * s2;
            mM[c] = nm;
        }
    }

    if (lane == 0) {
        const bool nonempty = hi > lo;
#pragma unroll
        for (int c = 0; c < 8; ++c)
            xmil[(size_t)n * 8 + c] = nonempty ? (aA[c] / lL[c]) : 0.f;
    }
}

// Pass 3: fused stats + output. Every block redundantly computes the
// per-channel mean / rstd (ddof=1) over xmil (128 KB, L2/L3-hot) and
// b = rms(beta_z), then writes its 256-element slice of out.
__global__ __launch_bounds__(256) void mixmil_statsout(
    const float* __restrict__ xmil,
    const float* __restrict__ bz,
    int N, int total,
    float* __restrict__ out)
{
    double s[8], qq[8];
    float t2[8];
#pragma unroll
    for (int c = 0; c < 8; ++c) { s[c] = 0.0; qq[c] = 0.0; t2[c] = 0.f; }

    for (int r = threadIdx.x; r < N; r += 256) {
        const float* row = xmil + (size_t)r * 8;
#pragma unroll
        for (int c = 0; c < 8; ++c) {
            float v = row[c];
            s[c] += v;
            qq[c] += (double)v * (double)v;
        }
    }
    for (int r = threadIdx.x; r < QDIM; r += 256) {
        const float* row = bz + (size_t)r * 8;
#pragma unroll
        for (int c = 0; c < 8; ++c) { float v = row[c]; t2[c] = fmaf(v, v, t2[c]); }
    }

    // wave reduce (width 64)
    for (int off = 32; off; off >>= 1) {
#pragma unroll
        for (int c = 0; c < 8; ++c) {
            s[c]  += __shfl_xor(s[c], off);
            qq[c] += __shfl_xor(qq[c], off);
            t2[c] += __shfl_xor(t2[c], off);
        }
    }

    __shared__ double S[4][8], QQ[4][8];
    __shared__ float T2[4][8];
    __shared__ float fb[8], fm[8], fr[8];
    const int w = threadIdx.x >> 6;
    if ((threadIdx.x & 63) == 0) {
#pragma unroll
        for (int c = 0; c < 8; ++c) { S[w][c] = s[c]; QQ[w][c] = qq[c]; T2[w][c] = t2[c]; }
    }
    __syncthreads();
    if (threadIdx.x < 8) {
        const int c = threadIdx.x;
        double ss = S[0][c] + S[1][c] + S[2][c] + S[3][c];
        double qs = QQ[0][c] + QQ[1][c] + QQ[2][c] + QQ[3][c];
        float  tt = T2[0][c] + T2[1][c] + T2[2][c] + T2[3][c];
        double mean = ss / (double)N;
        double var  = (qs - ss * ss / (double)N) / (double)(N - 1);
        fb[c] = sqrtf(tt / (float)QDIM);        // b
        fm[c] = (float)mean;
        fr[c] = (float)(1.0 / sqrt(var));       // rstd
    }
    __syncthreads();

    const int e = blockIdx.x * 256 + threadIdx.x;
    if (e < total) {
        const int c = e & 7;
        out[e] = fb[c] * (xmil[e] - fm[c]) * fr[c];
    }
}

extern "C" void kernel_launch(void* const* d_in, const int* in_sizes, int n_in,
                              void* d_out, int out_size, void* d_ws, size_t ws_size,
                              hipStream_t stream) {
    const float* x  = (const float*)d_in[0];
    const float* bu = (const float*)d_in[1];
    const float* bz = (const float*)d_in[2];
    const int*   sg = (const int*)d_in[3];   // sorted bag ids (int32)

    const int I = in_sizes[0] / QDIM;        // 512000
    const int N = out_size / C8;             // 4000 bags
    const int qI = I >> 2;                   // 128000

    // ws layout: uz[I*16] | xmil[N*8] | bs[N+1]   (ws ~1 GB, ~33 MB used)
    float* uz   = (float*)d_ws;
    float* xmil = uz + (size_t)I * 16;
    int*   bs   = (int*)(xmil + (size_t)N * C8);

    mixmil_proj<<<(qI + 255) / 256, 256, 0, stream>>>(x, bu, bz, sg, I, N, bs, uz);

    mixmil_bags2<<<(N + 3) / 4, 256, 0, stream>>>(uz, bs, N, xmil);

    const int total = N * C8;
    mixmil_statsout<<<(total + 255) / 256, 256, 0, stream>>>(
        xmil, bz, N, total, (float*)d_out);
}

// Round 10
// 111.309 us; speedup vs baseline: 3.1328x; 1.1312x over previous
//
#include <hip/hip_runtime.h>
#include <hip/hip_bf16.h>
#include <float.h>

// MixMIL fused kernel set.
// Shapes (fixed by setup_inputs): I=512000, Q=128, P=1, S=8 (C=8 channels), N=4000.
// d_in: x[I,Q] f32, beta_u[Q,1,8] f32, beta_z[Q,1,8] f32, i[I] int32 (sorted), n_bags
// d_out: [N,1,8] f32.
//
// Algebra: eta = beta_z/b and out = b*(xmil-mean)/std. std scales linearly with
// the positive per-channel b, so accumulating with raw beta_z (v = x.beta_z)
// gives xmil' = b*xmil and b*(xmil'-mean')/std' == b*(xmil-mean)/std. b only
// multiplies at the very end.
//
// R10 proj design rule learned over R6-R9: hipcc's default VGPR cap for this
// kernel is ~84 and every variant whose live set exceeded it spilled to
// scratch (R6 ~114 live, R7 ~140, R8 cap 64); R9's no-LDS variant instead
// fully unrolled into a ~70KB body (I-cache streaming). So: 2 rows/thread,
// chunk=16, NO explicit prefetch (TLP hides latency at 6 waves/EU), LDS
// weight broadcasts, live set ~80 regs, small loop body, no occupancy pragmas.

#define QDIM 128
#define C8 8

__device__ __forceinline__ void dot4(float& acc, const float4 a, const float4 b) {
    acc = fmaf(a.x, b.x, acc);
    acc = fmaf(a.y, b.y, acc);
    acc = fmaf(a.z, b.z, acc);
    acc = fmaf(a.w, b.w, acc);
}

// Pass 1: uz[r][0..7] = x[r].beta_u[:,c], uz[r][8..15] = x[r].beta_z[:,c].
// Thread g handles rows g and g+halfI. Bag bounds filled in prologue.
__global__ __launch_bounds__(256) void mixmil_proj(
    const float* __restrict__ x,
    const float* __restrict__ bu,
    const float* __restrict__ bz,
    const int*   __restrict__ seg,
    int I, int N,
    int* __restrict__ bs,
    float* __restrict__ uz)
{
    const int t    = threadIdx.x;
    const int gtid = blockIdx.x * 256 + t;
    const int nthr = gridDim.x * 256;

    // Fused bounds: bs[j] = first k with seg[k] >= j; bs[N] = I.
    for (int k = gtid; k <= I; k += nthr) {
        int a    = (k < I) ? seg[k]     : N;
        int prev = (k > 0) ? seg[k - 1] : -1;
        for (int j = prev + 1; j <= a; ++j) bs[j] = k;
    }

    __shared__ float WT[16][QDIM];  // rows 0..7: beta_u^T, rows 8..15: beta_z^T
    for (int j = t; j < QDIM * 16; j += 256) {
        int s = j >> 7, q = j & 127;
        WT[s][q] = (s < 8) ? bu[q * 8 + s] : bz[q * 8 + (s - 8)];
    }
    __syncthreads();

    const int halfI = I >> 1;
    const int g = gtid;
    if (g >= halfI) return;

    const float* xr1 = x + (size_t)g * QDIM;
    const float* xr2 = xr1 + (size_t)halfI * QDIM;

    float du1[8], dv1[8], du2[8], dv2[8];
#pragma unroll
    for (int c = 0; c < 8; ++c) { du1[c] = dv1[c] = du2[c] = dv2[c] = 0.f; }

#pragma unroll 2
    for (int q0 = 0; q0 < QDIM; q0 += 16) {
        // 64B-granular per-lane loads: one full cache line per row per iter.
        float4 xa[4], xb[4];
#pragma unroll
        for (int j = 0; j < 4; ++j) {
            xa[j] = *(const float4*)(xr1 + q0 + 4 * j);
            xb[j] = *(const float4*)(xr2 + q0 + 4 * j);
        }
#pragma unroll
        for (int c = 0; c < 8; ++c) {
#pragma unroll
            for (int j = 0; j < 4; ++j) {
                const float4 wu = *(const float4*)&WT[c][q0 + 4 * j];      // broadcast
                const float4 wz = *(const float4*)&WT[8 + c][q0 + 4 * j];  // broadcast
                dot4(du1[c], xa[j], wu);
                dot4(dv1[c], xa[j], wz);
                dot4(du2[c], xb[j], wu);
                dot4(dv2[c], xb[j], wz);
            }
        }
    }

    float4* o1 = (float4*)(uz + (size_t)g * 16);
    float4* o2 = (float4*)(uz + ((size_t)g + halfI) * 16);
    o1[0] = make_float4(du1[0], du1[1], du1[2], du1[3]);
    o1[1] = make_float4(du1[4], du1[5], du1[6], du1[7]);
    o1[2] = make_float4(dv1[0], dv1[1], dv1[2], dv1[3]);
    o1[3] = make_float4(dv1[4], dv1[5], dv1[6], dv1[7]);
    o2[0] = make_float4(du2[0], du2[1], du2[2], du2[3]);
    o2[1] = make_float4(du2[4], du2[5], du2[6], du2[7]);
    o2[2] = make_float4(dv2[0], dv2[1], dv2[2], dv2[3]);
    o2[3] = make_float4(dv2[4], dv2[5], dv2[6], dv2[7]);
}

// Pass 2: one bag per wave, online softmax + weighted sum over uz rows.
__global__ __launch_bounds__(256) void mixmil_bags2(
    const float* __restrict__ uz,
    const int*   __restrict__ bs,
    int N,
    float* __restrict__ xmil)  // [N,8]
{
    const int wave = threadIdx.x >> 6;
    const int lane = threadIdx.x & 63;
    const int n = blockIdx.x * 4 + wave;
    if (n >= N) return;

    const int lo = bs[n];
    const int hi = bs[n + 1];

    float mM[8], lL[8], aA[8];
#pragma unroll
    for (int c = 0; c < 8; ++c) { mM[c] = -1e30f; lL[c] = 0.f; aA[c] = 0.f; }

    for (int k = lo + lane; k < hi; k += 64) {
        const float4* r = (const float4*)(uz + (size_t)k * 16);
        float4 u0 = r[0], u1 = r[1], v0 = r[2], v1 = r[3];
        float uu[8] = {u0.x, u0.y, u0.z, u0.w, u1.x, u1.y, u1.z, u1.w};
        float vv[8] = {v0.x, v0.y, v0.z, v0.w, v1.x, v1.y, v1.z, v1.w};
#pragma unroll
        for (int c = 0; c < 8; ++c) {
            float u = uu[c], v = vv[c];
            float nm = fmaxf(mM[c], u);
            float sc = __expf(mM[c] - nm);
            float p  = __expf(u - nm);
            lL[c] = lL[c] * sc + p;
            aA[c] = aA[c] * sc + p * v;
            mM[c] = nm;
        }
    }

    // Butterfly merge across the 64 lanes of this wave.
    for (int off = 32; off; off >>= 1) {
#pragma unroll
        for (int c = 0; c < 8; ++c) {
            float m2 = __shfl_xor(mM[c], off);
            float l2 = __shfl_xor(lL[c], off);
            float a2 = __shfl_xor(aA[c], off);
            float nm = fmaxf(mM[c], m2);
            float s1 = __expf(mM[c] - nm);
            float s2 = __expf(m2 - nm);
            lL[c] = lL[c] * s1 + l2 * s2;
            aA[c] = aA[c] * s1 + a2 * s2;
            mM[c] = nm;
        }
    }

    if (lane == 0) {
        const bool nonempty = hi > lo;
#pragma unroll
        for (int c = 0; c < 8; ++c)
            xmil[(size_t)n * 8 + c] = nonempty ? (aA[c] / lL[c]) : 0.f;
    }
}

// Pass 3: fused stats + output. Every block redundantly computes the
// per-channel mean / rstd (ddof=1) over xmil (128 KB, L2/L3-hot) and
// b = rms(beta_z), then writes its 256-element slice of out.
__global__ __launch_bounds__(256) void mixmil_statsout(
    const float* __restrict__ xmil,
    const float* __restrict__ bz,
    int N, int total,
    float* __restrict__ out)
{
    double s[8], qq[8];
    float t2[8];
#pragma unroll
    for (int c = 0; c < 8; ++c) { s[c] = 0.0; qq[c] = 0.0; t2[c] = 0.f; }

    for (int r = threadIdx.x; r < N; r += 256) {
        const float* row = xmil + (size_t)r * 8;
#pragma unroll
        for (int c = 0; c < 8; ++c) {
            float v = row[c];
            s[c] += v;
            qq[c] += (double)v * (double)v;
        }
    }
    for (int r = threadIdx.x; r < QDIM; r += 256) {
        const float* row = bz + (size_t)r * 8;
#pragma unroll
        for (int c = 0; c < 8; ++c) { float v = row[c]; t2[c] = fmaf(v, v, t2[c]); }
    }

    // wave reduce (width 64)
    for (int off = 32; off; off >>= 1) {
#pragma unroll
        for (int c = 0; c < 8; ++c) {
            s[c]  += __shfl_xor(s[c], off);
            qq[c] += __shfl_xor(qq[c], off);
            t2[c] += __shfl_xor(t2[c], off);
        }
    }

    __shared__ double S[4][8], QQ[4][8];
    __shared__ float T2[4][8];
    __shared__ float fb[8], fm[8], fr[8];
    const int w = threadIdx.x >> 6;
    if ((threadIdx.x & 63) == 0) {
#pragma unroll
        for (int c = 0; c < 8; ++c) { S[w][c] = s[c]; QQ[w][c] = qq[c]; T2[w][c] = t2[c]; }
    }
    __syncthreads();
    if (threadIdx.x < 8) {
        const int c = threadIdx.x;
        double ss = S[0][c] + S[1][c] + S[2][c] + S[3][c];
        double qs = QQ[0][c] + QQ[1][c] + QQ[2][c] + QQ[3][c];
        float  tt = T2[0][c] + T2[1][c] + T2[2][c] + T2[3][c];
        double mean = ss / (double)N;
        double var  = (qs - ss * ss / (double)N) / (double)(N - 1);
        fb[c] = sqrtf(tt / (float)QDIM);        // b
        fm[c] = (float)mean;
        fr[c] = (float)(1.0 / sqrt(var));       // rstd
    }
    __syncthreads();

    const int e = blockIdx.x * 256 + threadIdx.x;
    if (e < total) {
        const int c = e & 7;
        out[e] = fb[c] * (xmil[e] - fm[c]) * fr[c];
    }
}

extern "C" void kernel_launch(void* const* d_in, const int* in_sizes, int n_in,
                              void* d_out, int out_size, void* d_ws, size_t ws_size,
                              hipStream_t stream) {
    const float* x  = (const float*)d_in[0];
    const float* bu = (const float*)d_in[1];
    const float* bz = (const float*)d_in[2];
    const int*   sg = (const int*)d_in[3];   // sorted bag ids (int32)

    const int I = in_sizes[0] / QDIM;        // 512000
    const int N = out_size / C8;             // 4000 bags
    const int halfI = I >> 1;                // 256000

    // ws layout: uz[I*16] | xmil[N*8] | bs[N+1]   (ws ~1 GB, ~33 MB used)
    float* uz   = (float*)d_ws;
    float* xmil = uz + (size_t)I * 16;
    int*   bs   = (int*)(xmil + (size_t)N * C8);

    mixmil_proj<<<(halfI + 255) / 256, 256, 0, stream>>>(x, bu, bz, sg, I, N, bs, uz);

    mixmil_bags2<<<(N + 3) / 4, 256, 0, stream>>>(uz, bs, N, xmil);

    const int total = N * C8;
    mixmil_statsout<<<(total + 255) / 256, 256, 0, stream>>>(
        xmil, bz, N, total, (float*)d_out);
}